// Round 1
// baseline (1615.286 us; speedup 1.0000x reference)
//
#include <hip/hip_runtime.h>

// ---------- helpers ----------
typedef __attribute__((ext_vector_type(8))) short short8;
typedef __attribute__((ext_vector_type(4))) float f32x4;

__device__ __forceinline__ unsigned short f2bf(float f) {
    unsigned int u = __float_as_uint(f);
    unsigned int r = (u + 0x7FFFu + ((u >> 16) & 1u)) >> 16;   // RNE
    return (unsigned short)r;
}

__device__ __forceinline__ void gload16(const void* g, void* l) {
    __builtin_amdgcn_global_load_lds(
        (const __attribute__((address_space(1))) unsigned int*)g,
        (__attribute__((address_space(3))) unsigned int*)l,
        16, 0, 0);
}

// ---------- Kernel 1: fused FC1 (fp32 GEMM, fp64-chunk accum) + LIF scan ----------
// grid (16 h-chunks, 256 batches), 256 threads.
// Tile: s=128 rows x h=128 cols, K=512.  Output: bf16 spikes [b][s][h] into ws.
__global__ __launch_bounds__(256) void k_fc1_scan(
    const float* __restrict__ x,    // [256][128][512]
    const float* __restrict__ W1,   // [2048][512]
    const float* __restrict__ b1,   // [2048]
    unsigned short* __restrict__ spk) // bf16 [256][128][2048]
{
    const int hc  = blockIdx.x;   // 0..15
    const int b   = blockIdx.y;   // 0..255
    const int tid = threadIdx.x;  // 0..255
    const int tx  = tid & 15;     // h micro-tile
    const int ty  = tid >> 4;     // s micro-tile

    // LDS: staging (AsT/BsT, 16x132 each) unioned with cur tile (128x132 f32)
    __shared__ float ldsbuf[128 * 132];                       // 67,584 B
    float (*AsT)[132] = (float (*)[132])ldsbuf;               // [16][132]
    float (*BsT)[132] = (float (*)[132])(ldsbuf + 16 * 132);  // [16][132]
    float (*cur)[132] = (float (*)[132])ldsbuf;               // [128][132]

    const float* xb  = x  + (size_t)b  * (128 * 512);
    const float* w1b = W1 + (size_t)hc * (128 * 512);

    float  acc[8][8];
    double accd[8][8];
#pragma unroll
    for (int i = 0; i < 8; ++i)
#pragma unroll
        for (int j = 0; j < 8; ++j) { acc[i][j] = 0.f; accd[i][j] = 0.0; }

    for (int k0 = 0; k0 < 512; k0 += 16) {
        __syncthreads();
        // stage 128x16 of A (x rows) and B (W1 rows), transposed into [k][row]
#pragma unroll
        for (int it = 0; it < 2; ++it) {
            int L   = tid + it * 256;     // 0..511
            int row = L >> 2;             // 0..127
            int kg  = L & 3;              // 0..3 (4 floats each)
            float4 av = *(const float4*)(xb  + (size_t)row * 512 + k0 + kg * 4);
            float4 bv = *(const float4*)(w1b + (size_t)row * 512 + k0 + kg * 4);
            AsT[kg * 4 + 0][row] = av.x; AsT[kg * 4 + 1][row] = av.y;
            AsT[kg * 4 + 2][row] = av.z; AsT[kg * 4 + 3][row] = av.w;
            BsT[kg * 4 + 0][row] = bv.x; BsT[kg * 4 + 1][row] = bv.y;
            BsT[kg * 4 + 2][row] = bv.z; BsT[kg * 4 + 3][row] = bv.w;
        }
        __syncthreads();
#pragma unroll
        for (int k = 0; k < 16; ++k) {
            const float4 a0 = *(const float4*)&AsT[k][ty * 8];
            const float4 a1 = *(const float4*)&AsT[k][ty * 8 + 4];
            const float4 c0 = *(const float4*)&BsT[k][tx * 8];
            const float4 c1 = *(const float4*)&BsT[k][tx * 8 + 4];
            const float av8[8] = {a0.x, a0.y, a0.z, a0.w, a1.x, a1.y, a1.z, a1.w};
            const float bv8[8] = {c0.x, c0.y, c0.z, c0.w, c1.x, c1.y, c1.z, c1.w};
#pragma unroll
            for (int i = 0; i < 8; ++i)
#pragma unroll
                for (int j = 0; j < 8; ++j)
                    acc[i][j] = fmaf(av8[i], bv8[j], acc[i][j]);
        }
        if ((k0 & 16) != 0) {  // flush every 32 K into fp64 accumulator
#pragma unroll
            for (int i = 0; i < 8; ++i)
#pragma unroll
                for (int j = 0; j < 8; ++j) {
                    accd[i][j] += (double)acc[i][j];
                    acc[i][j] = 0.f;
                }
        }
    }

    // dump tile to LDS (fp32) for the scan
    __syncthreads();
#pragma unroll
    for (int i = 0; i < 8; ++i)
#pragma unroll
        for (int j = 0; j < 8; ++j)
            cur[ty * 8 + i][tx * 8 + j] = (float)accd[i][j];
    __syncthreads();

    // LIF scan: one thread per h column, sequential over s, fp64 state
    if (tid < 128) {
        const int h = tid;
        const float  b1v = b1[hc * 128 + h];
        double mem = 0.0;
        size_t base = ((size_t)b * 128) * 2048 + (size_t)hc * 128 + h;
        for (int s = 0; s < 128; ++s) {
            float curf = cur[s][h] + b1v;
            double reset = (mem > 1.0) ? 1.0 : 0.0;
            mem = 0.9 * mem + (double)curf - reset;   // THRESHOLD = 1
            spk[base + (size_t)s * 2048] = (mem > 1.0) ? (unsigned short)0x3F80u
                                                       : (unsigned short)0u;
        }
    }
}

// ---------- Kernel 2: W2 fp32 -> bf16 ----------
__global__ __launch_bounds__(256) void k_cvt(const float* __restrict__ W2,
                                             unsigned short* __restrict__ W2b)
{
    int i = blockIdx.x * 256 + threadIdx.x;   // 262144 float4s
    float4 v = ((const float4*)W2)[i];
    ushort4 o;
    o.x = f2bf(v.x); o.y = f2bf(v.y); o.z = f2bf(v.z); o.w = f2bf(v.w);
    ((ushort4*)W2b)[i] = o;
}

// ---------- Kernel 3: FC2 bf16 MFMA GEMM (m97-style 128^2 tile, BK=32) ----------
// C[m][n] = sum_k A[m][k]*B[n][k] + b2[n];  A=spk [32768][2048], B=W2b [512][2048]
__global__ __launch_bounds__(256) void k_fc2(
    const unsigned short* __restrict__ A,   // bf16 spikes
    const unsigned short* __restrict__ B,   // bf16 W2
    const float* __restrict__ b2,           // [512]
    float* __restrict__ out)                // [32768][512]
{
    __shared__ char lds[16384];
    char* As = lds;          // [128][32] bf16 = 8192 B, row = 64 B
    char* Bs = lds + 8192;   // [128][32] bf16

    const int tid  = threadIdx.x;
    const int m0   = blockIdx.y * 128;
    const int n0   = blockIdx.x * 128;
    const int lane = tid & 63;
    const int wv   = tid >> 6;
    const int wm   = wv >> 1, wn = wv & 1;   // 2x2 waves of 64x64
    const int lr   = lane & 15;              // frag row
    const int lk   = lane >> 4;              // k-group (8 elems)

    f32x4 acc[4][4] = {};

    const char* gA = (const char*)(A + (size_t)m0 * 2048);  // row stride 4096 B
    const char* gB = (const char*)(B + (size_t)n0 * 2048);

    for (int kt = 0; kt < 64; ++kt) {
        const int kb = kt * 64;   // byte offset within a row (32 elems)
        __syncthreads();          // previous compute done before overwriting LDS
#pragma unroll
        for (int inst = 0; inst < 2; ++inst) {
            int o   = tid * 16 + inst * 4096;   // linear LDS byte offset
            int row = o >> 6;
            int cb  = o & 63;
            gload16(gA + (size_t)row * 4096 + kb + cb, As + o);
            gload16(gB + (size_t)row * 4096 + kb + cb, Bs + o);
        }
        __syncthreads();          // loads drained (vmcnt0 before barrier)

        short8 af[4], bf[4];
#pragma unroll
        for (int mi = 0; mi < 4; ++mi)
            af[mi] = *(const short8*)(As + (wm * 64 + mi * 16 + lr) * 64 + lk * 16);
#pragma unroll
        for (int ni = 0; ni < 4; ++ni)
            bf[ni] = *(const short8*)(Bs + (wn * 64 + ni * 16 + lr) * 64 + lk * 16);
#pragma unroll
        for (int mi = 0; mi < 4; ++mi)
#pragma unroll
            for (int ni = 0; ni < 4; ++ni)
                acc[mi][ni] = __builtin_amdgcn_mfma_f32_16x16x32_bf16(
                    af[mi], bf[ni], acc[mi][ni], 0, 0, 0);
    }

    float b2v[4];
#pragma unroll
    for (int ni = 0; ni < 4; ++ni) b2v[ni] = b2[n0 + wn * 64 + ni * 16 + lr];

#pragma unroll
    for (int mi = 0; mi < 4; ++mi) {
        const int rb = m0 + wm * 64 + mi * 16 + lk * 4;
#pragma unroll
        for (int ni = 0; ni < 4; ++ni) {
            const int c = n0 + wn * 64 + ni * 16 + lr;
#pragma unroll
            for (int r = 0; r < 4; ++r)
                out[(size_t)(rb + r) * 512 + c] = acc[mi][ni][r] + b2v[ni];
        }
    }
}

// ---------- launch ----------
extern "C" void kernel_launch(void* const* d_in, const int* in_sizes, int n_in,
                              void* d_out, int out_size, void* d_ws, size_t ws_size,
                              hipStream_t stream) {
    const float* x  = (const float*)d_in[0];   // [256][128][512]
    const float* W1 = (const float*)d_in[1];   // [2048][512]
    const float* b1 = (const float*)d_in[2];   // [2048]
    const float* W2 = (const float*)d_in[3];   // [512][2048]
    const float* b2 = (const float*)d_in[4];   // [512]
    float* out = (float*)d_out;                // [256][128][512]

    unsigned short* spk = (unsigned short*)d_ws;                       // 128 MiB bf16
    unsigned short* W2b = (unsigned short*)((char*)d_ws + 134217728);  // 2 MiB bf16

    k_fc1_scan<<<dim3(16, 256), 256, 0, stream>>>(x, W1, b1, spk);
    k_cvt    <<<dim3(1024),     256, 0, stream>>>(W2, W2b);
    k_fc2    <<<dim3(4, 256),   256, 0, stream>>>(spk, W2b, b2, out);
}